// Round 24
// baseline (124.137 us; speedup 1.0000x reference)
//
#include <hip/hip_runtime.h>
#include <stdint.h>

typedef __attribute__((ext_vector_type(4))) float f32x4;
typedef __attribute__((ext_vector_type(8))) short bf16x8;
typedef __attribute__((ext_vector_type(4))) short bf16x4;

#define DEV static __device__ __forceinline__

DEV short f2bf(float f) {
  union { float f; uint32_t u; } x; x.f = f;
  uint32_t r = (x.u + 0x7fffu + ((x.u >> 16) & 1u)) >> 16;
  return (short)r;
}

DEV void gload16(const void* g, void* l) {
  __builtin_amdgcn_global_load_lds(
      (const __attribute__((address_space(1))) uint32_t*)g,
      (__attribute__((address_space(3))) uint32_t*)l, 16, 0, 0);
}

#define MFMA16(a, b, c) __builtin_amdgcn_mfma_f32_16x16x32_bf16((a), (b), (c), 0, 0, 0)
#define WAITV(n) asm volatile("s_waitcnt vmcnt(" #n ")" ::: "memory")
#define BAR() __builtin_amdgcn_s_barrier()

// ---------------- fp32 -> bf16 convert (WEIGHTS ONLY: Wq, Wkv, Wproj) --------------
// x/y conversion fused into qkv_gemm (in-register, same f2bf -> bit-identical).
__global__ void convert_all(const float* __restrict__ wq, const float* __restrict__ wkv,
                            const float* __restrict__ wp, short* __restrict__ ws)
{
  const long NQ = 589824L, NKV = 1179648L, NP = 589824L;
  short* wqb  = ws + 12582912L;   // layout unchanged: xb/yb slots left unused
  short* wkvb = wqb + NQ;
  short* wpb  = wkvb + NKV;
  const long total4 = (NQ + NKV + NP) / 4;
  const long stride = (long)gridDim.x * blockDim.x;
  for (long i = (long)blockIdx.x * blockDim.x + threadIdx.x; i < total4; i += stride) {
    long e = i * 4;
    const float* src; short* dst; long off;
    if (e < NQ)           { src = wq;  dst = wqb;  off = e; }
    else if (e < NQ + NKV){ src = wkv; dst = wkvb; off = e - NQ; }
    else                  { src = wp;  dst = wpb;  off = e - NQ - NKV; }
    const f32x4 v = *(const f32x4*)(src + off);
    bf16x4 o;
    o[0] = f2bf(v[0]); o[1] = f2bf(v[1]); o[2] = f2bf(v[2]); o[3] = f2bf(v[3]);
    *(bf16x4*)(dst + off) = o;
  }
}

// ---------------- QKV GEMM v8: fp32-A fused convert, 128x256, BK=32, dbuf 64KB ----
// A staged fp32 (16KB/buf, swz (row&7)<<4 on 128B rows), converted to bf16 in
// registers at fragment read (bit-identical to pre-converted path). B staged bf16.
// STAGE = 8 loads -> WAITV(8). launch_bounds (256,2): round-16 spill lesson.
__global__ __launch_bounds__(256, 2) void qkv_gemm(
    const float* __restrict__ xf, const float* __restrict__ yf,
    const short* __restrict__ wqb, const short* __restrict__ wkvb,
    short* __restrict__ qb, short* __restrict__ kb, short* __restrict__ vT)
{
  __shared__ __align__(16) char lds[65536];
  const int t = threadIdx.x;
  const int wv = t >> 6, lane = t & 63;
  const int c = lane & 15, g = lane >> 4;
  const int wm = wv >> 1, wn = wv & 1;
  const int bm = blockIdx.x, bj = blockIdx.y;
  const int mode = bj / 3, jj = bj % 3;

  const float* Af = (mode == 0) ? xf : yf;
  const short* W;
  if (mode == 0)      W = wqb  + (size_t)jj * 196608;
  else if (mode == 1) W = wkvb + (size_t)jj * 196608;
  else                W = wkvb + 589824 + (size_t)jj * 196608;

  const int am0 = bm * 128;
  const f32x4 z4 = {0.f, 0.f, 0.f, 0.f};
  f32x4 acc[4][8];
#pragma unroll
  for (int i = 0; i < 4; i++)
#pragma unroll
    for (int j = 0; j < 8; j++) acc[i][j] = z4;

  // A fragments: two 16B fp32 reads per fragment (elements g*8..+3, g*8+4..+7)
  int aoff0[4], aoff1[4], boff[8];
#pragma unroll
  for (int mf = 0; mf < 4; mf++) {
    const int row = wm * 64 + mf * 16 + c;
    const int s = (row & 7) << 4;
    aoff0[mf] = row * 128 + ((g * 32) ^ s);
    aoff1[mf] = row * 128 + ((g * 32 + 16) ^ s);
  }
#pragma unroll
  for (int nf = 0; nf < 8; nf++) {
    const int row = wn * 128 + nf * 16 + c;
    boff[nf] = row * 64 + ((g * 16) ^ ((row & 3) << 4));
  }

  auto STAGE = [&](int kt, int p) {
    char* lA = lds + p * 32768;   // fp32 A tile: [128 rows][128B], swizzled
    char* lB = lA + 16384;        // bf16 B tile: [256 rows][64B], swizzled
#pragma unroll
    for (int i = 0; i < 4; i++) {
      const int cb0 = (i * 4 + wv) * 1024;
      const int o = cb0 + lane * 16;
      const int row = o >> 7;
      const int cbyte = (o & 127) ^ ((row & 7) << 4);
      gload16((const char*)Af + ((size_t)(am0 + row) * 768 + kt) * 4 + cbyte, lA + cb0);
    }
#pragma unroll
    for (int i = 0; i < 4; i++) {
      const int cb0 = (i * 4 + wv) * 1024;
      const int o = cb0 + lane * 16;
      const int row = o >> 6;
      const int cbyte = (o & 63) ^ ((row & 3) << 4);
      gload16((const char*)W + ((size_t)row * 768 + kt) * 2 + cbyte, lB + cb0);
    }
  };
  auto COMPUTE = [&](int p) {
    char* lA = lds + p * 32768;
    char* lB = lA + 16384;
    bf16x8 af[4], bfr[8];
#pragma unroll
    for (int mf = 0; mf < 4; mf++) {
      const f32x4 alo = *(const f32x4*)(lA + aoff0[mf]);
      const f32x4 ahi = *(const f32x4*)(lA + aoff1[mf]);
      bf16x8 a;
#pragma unroll
      for (int e = 0; e < 4; e++) { a[e] = f2bf(alo[e]); a[4 + e] = f2bf(ahi[e]); }
      af[mf] = a;
    }
#pragma unroll
    for (int nf = 0; nf < 8; nf++) bfr[nf] = *(const bf16x8*)(lB + boff[nf]);
    __builtin_amdgcn_s_setprio(1);
#pragma unroll
    for (int mf = 0; mf < 4; mf++)
#pragma unroll
      for (int nf = 0; nf < 8; nf++)
        acc[mf][nf] = MFMA16(af[mf], bfr[nf], acc[mf][nf]);
    __builtin_amdgcn_s_setprio(0);
  };

  STAGE(0, 0);
  WAITV(0); BAR();
#pragma unroll 2
  for (int it = 0; it < 23; it++) {
    STAGE((it + 1) * 32, (it + 1) & 1);
    WAITV(8); BAR();
    COMPUTE(it & 1);
    BAR();
  }
  WAITV(0); BAR();
  COMPUTE(1);
  __syncthreads();   // staging fully consumed; epilogue reuses lds

  const int b = bm >> 3;
  const int nloc0 = (bm & 7) * 128;
  const int h = jj * 2 + wn;

  if (mode <= 1) {
    float sc[4][4];
#pragma unroll
    for (int mf = 0; mf < 4; mf++)
#pragma unroll
      for (int r = 0; r < 4; r++) {
        float s = 0.f;
#pragma unroll
        for (int nf = 0; nf < 8; nf++) { float v = acc[mf][nf][r]; s += v * v; }
        s += __shfl_xor(s, 1); s += __shfl_xor(s, 2);
        s += __shfl_xor(s, 4); s += __shfl_xor(s, 8);
        sc[mf][r] = 1.0f / fmaxf(sqrtf(s), 1e-12f);
      }
    short* lEw = (short*)(lds + wv * 8704);   // 32 rows x 136 shorts, wave-private
    short* dst = (mode == 0) ? qb : kb;
    for (int half = 0; half < 2; half++) {
#pragma unroll
      for (int mfi = 0; mfi < 2; mfi++) {
        const int mf = half * 2 + mfi;
#pragma unroll
        for (int nf = 0; nf < 8; nf++)
#pragma unroll
          for (int r = 0; r < 4; r++)
            lEw[(mfi*16 + 4*g + r) * 136 + nf*16 + c] = f2bf(acc[mf][nf][r] * sc[mf][r]);
      }
      const size_t base = ((size_t)(b * 6 + h) * 1024 + nloc0 + wm * 64 + half * 32) * 128;
#pragma unroll
      for (int itr = 0; itr < 8; itr++) {
        const int slot = itr * 64 + lane;
        const int row = slot >> 4, ch = slot & 15;
        bf16x8 v = *(const bf16x8*)&lEw[row * 136 + ch * 8];
        *(bf16x8*)(dst + base + (size_t)row * 128 + ch * 8) = v;
      }
    }
  } else {
    short* lEt = (short*)(lds + wv * 9216);   // 64 d-rows x 72 shorts, wave-private
    const size_t dbase = (size_t)(b * 6 + h) * 128 * 1024 + nloc0 + wm * 64;
    for (int half = 0; half < 2; half++) {
#pragma unroll
      for (int mf = 0; mf < 4; mf++)
#pragma unroll
        for (int nfi = 0; nfi < 4; nfi++) {
          const int nf = half * 4 + nfi;
          bf16x4 p;
#pragma unroll
          for (int r = 0; r < 4; r++) p[r] = f2bf(acc[mf][nf][r]);
          *(bf16x4*)&lEt[(nfi*16 + c) * 72 + mf*16 + 4*g] = p;
        }
#pragma unroll
      for (int itr = 0; itr < 8; itr++) {
        const int slot = itr * 64 + lane;
        const int d = slot >> 3, ch = slot & 7;
        bf16x8 v = *(const bf16x8*)&lEt[d * 72 + ch * 8];
        *(bf16x8*)(vT + dbase + (size_t)(half * 64 + d) * 1024 + ch * 8) = v;
      }
    }
  }
}

// ---------------- attention v8 (measured known-good) ------------------------------
__global__ __launch_bounds__(256, 2) void attn_fwd(
    const short* __restrict__ qb, const short* __restrict__ kb,
    const short* __restrict__ vT, const float* __restrict__ temp,
    short* __restrict__ ob)
{
  __shared__ __align__(16) char lds[37888];
  const int t = threadIdx.x;
  const int wv = t >> 6, lane = t & 63;
  const int c = lane & 15, g = lane >> 4;
  const int bid = blockIdx.x;
  const int work = (bid & 7) * 96 + (bid >> 3);   // bijective: 768 = 8 XCD x 96
  const int bh = work >> 4, qt = work & 15;
  const int b = bh / 6, h = bh % 6;
  short* myP = (short*)(lds + 32768 + wv * 1280);  // [16 q][40 shorts]

  const short* qbase = qb + (size_t)bh * 131072;
  const char*  kgl   = (const char*)(kb + (size_t)bh * 131072);
  const char*  vgl   = (const char*)(vT + (size_t)bh * 131072);
  const int q0 = qt * 64 + wv * 16;

  bf16x8 qf[4];
#pragma unroll
  for (int dc = 0; dc < 4; dc++)
    qf[dc] = *(const bf16x8*)(qbase + (size_t)(q0 + c) * 128 + dc*32 + g*8);

  int koff[8], voff[8];
#pragma unroll
  for (int kf = 0; kf < 2; kf++)
#pragma unroll
    for (int kc = 0; kc < 4; kc++) {
      const int row = kf * 16 + c;
      koff[kf*4 + kc] = row * 256 + ((kc * 64 + g * 16) ^ ((row & 7) << 4));
    }
#pragma unroll
  for (int df = 0; df < 8; df++) {
    const int d = df * 16 + c;
    voff[df] = d * 64 + ((g * 16) ^ (((d >> 1) & 3) << 4));
  }
  const int paoff = c * 40 + g * 8;
  const int pwbase = 4 * g * 40 + c;

  const float t2 = temp[h] * 1.44269504088896341f;
  const f32x4 z4 = {0.f, 0.f, 0.f, 0.f};
  f32x4 oacc[8];
#pragma unroll
  for (int j = 0; j < 8; j++) oacc[j] = z4;
  float lsum[4] = {0.f, 0.f, 0.f, 0.f};

  auto STAGE = [&](int kt, int p) {
    char* kbuf = lds + p * 16384;
    char* vbuf = kbuf + 8192;
#pragma unroll
    for (int i = 0; i < 2; i++) {
      const int ob_ = (i * 4 + wv) * 1024;
      const int o = ob_ + lane * 16;
      {
        const int row = o >> 8;
        const int cb = (o & 255) ^ ((row & 7) << 4);
        gload16(kgl + (size_t)(kt + row) * 256 + cb, kbuf + ob_);
      }
      {
        const int d = o >> 6;
        const int cb = (o & 63) ^ (((d >> 1) & 3) << 4);
        gload16(vgl + (size_t)d * 2048 + (size_t)kt * 2 + cb, vbuf + ob_);
      }
    }
  };
  auto COMPUTE = [&](int p) {
    char* kbuf = lds + p * 16384;
    char* vbuf = kbuf + 8192;
    f32x4 s[2] = {z4, z4};
#pragma unroll
    for (int kf = 0; kf < 2; kf++) {
      bf16x8 kfr[4];
#pragma unroll
      for (int kc = 0; kc < 4; kc++)
        kfr[kc] = *(const bf16x8*)(kbuf + koff[kf*4 + kc]);
      __builtin_amdgcn_s_setprio(1);
#pragma unroll
      for (int kc = 0; kc < 4; kc++)
        s[kf] = MFMA16(qf[kc], kfr[kc], s[kf]);
      __builtin_amdgcn_s_setprio(0);
    }
    bf16x8 vf[8];
#pragma unroll
    for (int df = 0; df < 8; df++)
      vf[df] = *(const bf16x8*)(vbuf + voff[df]);
#pragma unroll
    for (int kf = 0; kf < 2; kf++)
#pragma unroll
      for (int r = 0; r < 4; r++) {
        float pv = __builtin_amdgcn_exp2f(s[kf][r] * t2);
        lsum[r] += pv;
        myP[pwbase + r * 40 + kf * 16] = f2bf(pv);
      }
    bf16x8 pa = *(const bf16x8*)&myP[paoff];
    __builtin_amdgcn_s_setprio(1);
#pragma unroll
    for (int df = 0; df < 8; df++)
      oacc[df] = MFMA16(pa, vf[df], oacc[df]);
    __builtin_amdgcn_s_setprio(0);
  };

  STAGE(0, 0);
  WAITV(0); BAR();
#pragma unroll 2
  for (int it = 0; it < 31; it++) {
    STAGE((it + 1) * 32, (it + 1) & 1);
    WAITV(4); BAR();
    COMPUTE(it & 1);
    BAR();
  }
  WAITV(0); BAR();
  COMPUTE(1);

  float rin[4];
#pragma unroll
  for (int r = 0; r < 4; r++) {
    float s = lsum[r];
    s += __shfl_xor(s, 1); s += __shfl_xor(s, 2);
    s += __shfl_xor(s, 4); s += __shfl_xor(s, 8);
    rin[r] = 1.0f / s;
  }
  __syncthreads();
  short* myO = (short*)(lds + wv * 4352);
#pragma unroll
  for (int df = 0; df < 8; df++)
#pragma unroll
    for (int r = 0; r < 4; r++)
      myO[(4*g + r) * 136 + df*16 + c] = f2bf(oacc[df][r] * rin[r]);
  const size_t obase_ = ((size_t)(b * 1024 + q0)) * 768 + h * 128;
#pragma unroll
  for (int it = 0; it < 4; it++) {
    const int slot = it * 64 + lane;
    const int row = slot >> 4, ch = slot & 15;
    bf16x8 v = *(const bf16x8*)&myO[row * 136 + ch * 8];
    *(bf16x8*)(ob + obase_ + (size_t)row * 768 + ch * 8) = v;
  }
}

// ---------------- proj GEMM v4 (measured known-good): 128x256, BK=32, dbuf --------
__global__ __launch_bounds__(256, 2) void proj_gemm(
    const short* __restrict__ ob, const short* __restrict__ wpb,
    const float* __restrict__ bias, float* __restrict__ out)
{
  __shared__ __align__(16) char lds[49152];
  const int t = threadIdx.x;
  const int wv = t >> 6, lane = t & 63;
  const int c = lane & 15, g = lane >> 4;
  const int wm = wv >> 1, wn = wv & 1;
  const int bm = blockIdx.x, bj = blockIdx.y;
  const short* W = wpb + (size_t)bj * 196608;
  const int am0 = bm * 128;
  const f32x4 z4 = {0.f, 0.f, 0.f, 0.f};
  f32x4 acc[4][8];
#pragma unroll
  for (int i = 0; i < 4; i++)
#pragma unroll
    for (int j = 0; j < 8; j++) acc[i][j] = z4;

  int aoff[4], boff[8];
#pragma unroll
  for (int mf = 0; mf < 4; mf++) {
    const int row = wm * 64 + mf * 16 + c;
    aoff[mf] = row * 64 + ((g * 16) ^ ((row & 3) << 4));
  }
#pragma unroll
  for (int nf = 0; nf < 8; nf++) {
    const int row = wn * 128 + nf * 16 + c;
    boff[nf] = row * 64 + ((g * 16) ^ ((row & 3) << 4));
  }

  auto STAGE = [&](int kt, int p) {
    char* lA = lds + p * 24576;
    char* lB = lA + 8192;
#pragma unroll
    for (int i = 0; i < 2; i++) {
      const int cb0 = (i * 4 + wv) * 1024;
      const int o = cb0 + lane * 16;
      const int row = o >> 6;
      const int cbyte = (o & 63) ^ ((row & 3) << 4);
      gload16((const char*)ob + ((size_t)(am0 + row) * 768 + kt) * 2 + cbyte, lA + cb0);
    }
#pragma unroll
    for (int i = 0; i < 4; i++) {
      const int cb0 = (i * 4 + wv) * 1024;
      const int o = cb0 + lane * 16;
      const int row = o >> 6;
      const int cbyte = (o & 63) ^ ((row & 3) << 4);
      gload16((const char*)W + ((size_t)row * 768 + kt) * 2 + cbyte, lB + cb0);
    }
  };
  auto COMPUTE = [&](int p) {
    char* lA = lds + p * 24576;
    char* lB = lA + 8192;
    bf16x8 af[4], bfr[8];
#pragma unroll
    for (int mf = 0; mf < 4; mf++) af[mf] = *(const bf16x8*)(lA + aoff[mf]);
#pragma unroll
    for (int nf = 0; nf < 8; nf++) bfr[nf] = *(const bf16x8*)(lB + boff[nf]);
    __builtin_amdgcn_s_setprio(1);
#pragma unroll
    for (int mf = 0; mf < 4; mf++)
#pragma unroll
      for (int nf = 0; nf < 8; nf++)
        acc[mf][nf] = MFMA16(af[mf], bfr[nf], acc[mf][nf]);
    __builtin_amdgcn_s_setprio(0);
  };

  STAGE(0, 0);
  WAITV(0); BAR();
#pragma unroll 2
  for (int it = 0; it < 23; it++) {
    STAGE((it + 1) * 32, (it + 1) & 1);
    WAITV(6); BAR();
    COMPUTE(it & 1);
    BAR();
  }
  WAITV(0); BAR();
  COMPUTE(1);

  const int col0 = bj * 256 + wn * 128;
  float bb[8];
#pragma unroll
  for (int nf = 0; nf < 8; nf++) bb[nf] = bias[col0 + nf*16 + c];
#pragma unroll
  for (int mf = 0; mf < 4; mf++)
#pragma unroll
    for (int nf = 0; nf < 8; nf++)
#pragma unroll
      for (int r = 0; r < 4; r++)
        out[(size_t)(am0 + wm*64 + mf*16 + 4*g + r) * 768 + col0 + nf*16 + c]
            = acc[mf][nf][r] + bb[nf];
}

extern "C" void kernel_launch(void* const* d_in, const int* in_sizes, int n_in,
                              void* d_out, int out_size, void* d_ws, size_t ws_size,
                              hipStream_t stream) {
  const float* x    = (const float*)d_in[0];
  const float* y    = (const float*)d_in[1];
  const float* wq   = (const float*)d_in[2];
  const float* wkv  = (const float*)d_in[3];
  const float* wp   = (const float*)d_in[4];
  const float* bias = (const float*)d_in[5];
  const float* temp = (const float*)d_in[6];

  short* ws   = (short*)d_ws;
  short* wqb  = ws + 12582912;     // xb/yb slots unused (fused into qkv)
  short* wkvb = wqb + 589824;
  short* wpb  = wkvb + 1179648;
  short* qb   = wpb + 589824;
  short* kb   = qb + 6291456;
  short* vT   = kb + 6291456;
  short* ob   = vT + 6291456;

  convert_all<<<dim3(512), dim3(256), 0, stream>>>(wq, wkv, wp, ws);
  qkv_gemm<<<dim3(64, 9), dim3(256), 0, stream>>>(x, y, wqb, wkvb, qb, kb, vT);
  attn_fwd<<<dim3(768), dim3(256), 0, stream>>>(qb, kb, vT, temp, ob);
  proj_gemm<<<dim3(64, 3), dim3(256), 0, stream>>>(ob, wpb, bias, (float*)d_out);
}

// Round 25
// 123.994 us; speedup vs baseline: 1.0012x; 1.0012x over previous
//
#include <hip/hip_runtime.h>
#include <stdint.h>

typedef __attribute__((ext_vector_type(4))) float f32x4;
typedef __attribute__((ext_vector_type(8))) short bf16x8;
typedef __attribute__((ext_vector_type(4))) short bf16x4;

#define DEV static __device__ __forceinline__

DEV short f2bf(float f) {
  union { float f; uint32_t u; } x; x.f = f;
  uint32_t r = (x.u + 0x7fffu + ((x.u >> 16) & 1u)) >> 16;
  return (short)r;
}

DEV void gload16(const void* g, void* l) {
  __builtin_amdgcn_global_load_lds(
      (const __attribute__((address_space(1))) uint32_t*)g,
      (__attribute__((address_space(3))) uint32_t*)l, 16, 0, 0);
}

#define MFMA16(a, b, c) __builtin_amdgcn_mfma_f32_16x16x32_bf16((a), (b), (c), 0, 0, 0)
#define WAITV(n) asm volatile("s_waitcnt vmcnt(" #n ")" ::: "memory")
#define BAR() __builtin_amdgcn_s_barrier()

// ---------------- fp32 -> bf16 convert (x, y, Wq, Wkv, Wproj) ----------------
__global__ void convert_all(const float* __restrict__ x, const float* __restrict__ y,
                            const float* __restrict__ wq, const float* __restrict__ wkv,
                            const float* __restrict__ wp, short* __restrict__ ws)
{
  const long NX = 6291456L, NY = 6291456L, NQ = 589824L, NKV = 1179648L, NP = 589824L;
  short* xb = ws;
  short* yb = xb + NX;
  short* wqb = yb + NY;
  short* wkvb = wqb + NQ;
  short* wpb = wkvb + NKV;
  const long total4 = (NX + NY + NQ + NKV + NP) / 4;
  const long stride = (long)gridDim.x * blockDim.x;
  for (long i = (long)blockIdx.x * blockDim.x + threadIdx.x; i < total4; i += stride) {
    long e = i * 4;
    const float* src; short* dst; long off;
    if (e < NX)                 { src = x;   dst = xb;   off = e; }
    else if (e < NX + NY)       { src = y;   dst = yb;   off = e - NX; }
    else if (e < NX + NY + NQ)  { src = wq;  dst = wqb;  off = e - NX - NY; }
    else if (e < NX + NY + NQ + NKV) { src = wkv; dst = wkvb; off = e - NX - NY - NQ; }
    else                        { src = wp;  dst = wpb;  off = e - NX - NY - NQ - NKV; }
    const f32x4 v = *(const f32x4*)(src + off);
    bf16x4 o;
    o[0] = f2bf(v[0]); o[1] = f2bf(v[1]); o[2] = f2bf(v[2]); o[3] = f2bf(v[3]);
    *(bf16x4*)(dst + off) = o;
  }
}

// ---------------- QKV GEMM v4 (measured 124.02 config): 128x256, BK=32, dbuf 49KB -
// launch_bounds MUST stay (256,2): (256,3) clamps VGPR to 84 (<160 live) -> spill.
// fp32-A fused convert REJECTED by measurement (round 24: qkv 50->63.5us).
__global__ __launch_bounds__(256, 2) void qkv_gemm(
    const short* __restrict__ xb, const short* __restrict__ yb,
    const short* __restrict__ wqb, const short* __restrict__ wkvb,
    short* __restrict__ qb, short* __restrict__ kb, short* __restrict__ vT)
{
  __shared__ __align__(16) char lds[49152];
  const int t = threadIdx.x;
  const int wv = t >> 6, lane = t & 63;
  const int c = lane & 15, g = lane >> 4;
  const int wm = wv >> 1, wn = wv & 1;
  const int bm = blockIdx.x, bj = blockIdx.y;
  const int mode = bj / 3, jj = bj % 3;

  const short* A = (mode == 0) ? xb : yb;
  const short* W;
  if (mode == 0)      W = wqb  + (size_t)jj * 196608;
  else if (mode == 1) W = wkvb + (size_t)jj * 196608;
  else                W = wkvb + 589824 + (size_t)jj * 196608;

  const int am0 = bm * 128;
  const f32x4 z4 = {0.f, 0.f, 0.f, 0.f};
  f32x4 acc[4][8];
#pragma unroll
  for (int i = 0; i < 4; i++)
#pragma unroll
    for (int j = 0; j < 8; j++) acc[i][j] = z4;

  int aoff[4], boff[8];
#pragma unroll
  for (int mf = 0; mf < 4; mf++) {
    const int row = wm * 64 + mf * 16 + c;
    aoff[mf] = row * 64 + ((g * 16) ^ ((row & 3) << 4));
  }
#pragma unroll
  for (int nf = 0; nf < 8; nf++) {
    const int row = wn * 128 + nf * 16 + c;
    boff[nf] = row * 64 + ((g * 16) ^ ((row & 3) << 4));
  }

  auto STAGE = [&](int kt, int p) {
    char* lA = lds + p * 24576;
    char* lB = lA + 8192;
#pragma unroll
    for (int i = 0; i < 2; i++) {
      const int cb0 = (i * 4 + wv) * 1024;
      const int o = cb0 + lane * 16;
      const int row = o >> 6;
      const int cbyte = (o & 63) ^ ((row & 3) << 4);
      gload16((const char*)A + ((size_t)(am0 + row) * 768 + kt) * 2 + cbyte, lA + cb0);
    }
#pragma unroll
    for (int i = 0; i < 4; i++) {
      const int cb0 = (i * 4 + wv) * 1024;
      const int o = cb0 + lane * 16;
      const int row = o >> 6;
      const int cbyte = (o & 63) ^ ((row & 3) << 4);
      gload16((const char*)W + ((size_t)row * 768 + kt) * 2 + cbyte, lB + cb0);
    }
  };
  auto COMPUTE = [&](int p) {
    char* lA = lds + p * 24576;
    char* lB = lA + 8192;
    bf16x8 af[4], bfr[8];
#pragma unroll
    for (int mf = 0; mf < 4; mf++) af[mf] = *(const bf16x8*)(lA + aoff[mf]);
#pragma unroll
    for (int nf = 0; nf < 8; nf++) bfr[nf] = *(const bf16x8*)(lB + boff[nf]);
    __builtin_amdgcn_s_setprio(1);
#pragma unroll
    for (int mf = 0; mf < 4; mf++)
#pragma unroll
      for (int nf = 0; nf < 8; nf++)
        acc[mf][nf] = MFMA16(af[mf], bfr[nf], acc[mf][nf]);
    __builtin_amdgcn_s_setprio(0);
  };

  STAGE(0, 0);
  WAITV(0); BAR();
#pragma unroll 2
  for (int it = 0; it < 23; it++) {
    STAGE((it + 1) * 32, (it + 1) & 1);
    WAITV(6); BAR();
    COMPUTE(it & 1);
    BAR();
  }
  WAITV(0); BAR();
  COMPUTE(1);
  __syncthreads();   // staging fully consumed; epilogue reuses lds

  const int b = bm >> 3;
  const int nloc0 = (bm & 7) * 128;
  const int h = jj * 2 + wn;

  if (mode <= 1) {
    float sc[4][4];
#pragma unroll
    for (int mf = 0; mf < 4; mf++)
#pragma unroll
      for (int r = 0; r < 4; r++) {
        float s = 0.f;
#pragma unroll
        for (int nf = 0; nf < 8; nf++) { float v = acc[mf][nf][r]; s += v * v; }
        s += __shfl_xor(s, 1); s += __shfl_xor(s, 2);
        s += __shfl_xor(s, 4); s += __shfl_xor(s, 8);
        sc[mf][r] = 1.0f / fmaxf(sqrtf(s), 1e-12f);
      }
    short* lEw = (short*)(lds + wv * 8704);   // 32 rows x 136 shorts, wave-private
    short* dst = (mode == 0) ? qb : kb;
    for (int half = 0; half < 2; half++) {
#pragma unroll
      for (int mfi = 0; mfi < 2; mfi++) {
        const int mf = half * 2 + mfi;
#pragma unroll
        for (int nf = 0; nf < 8; nf++)
#pragma unroll
          for (int r = 0; r < 4; r++)
            lEw[(mfi*16 + 4*g + r) * 136 + nf*16 + c] = f2bf(acc[mf][nf][r] * sc[mf][r]);
      }
      const size_t base = ((size_t)(b * 6 + h) * 1024 + nloc0 + wm * 64 + half * 32) * 128;
#pragma unroll
      for (int itr = 0; itr < 8; itr++) {
        const int slot = itr * 64 + lane;
        const int row = slot >> 4, ch = slot & 15;
        bf16x8 v = *(const bf16x8*)&lEw[row * 136 + ch * 8];
        *(bf16x8*)(dst + base + (size_t)row * 128 + ch * 8) = v;
      }
    }
  } else {
    short* lEt = (short*)(lds + wv * 9216);   // 64 d-rows x 72 shorts, wave-private
    const size_t dbase = (size_t)(b * 6 + h) * 128 * 1024 + nloc0 + wm * 64;
    for (int half = 0; half < 2; half++) {
#pragma unroll
      for (int mf = 0; mf < 4; mf++)
#pragma unroll
        for (int nfi = 0; nfi < 4; nfi++) {
          const int nf = half * 4 + nfi;
          bf16x4 p;
#pragma unroll
          for (int r = 0; r < 4; r++) p[r] = f2bf(acc[mf][nf][r]);
          *(bf16x4*)&lEt[(nfi*16 + c) * 72 + mf*16 + 4*g] = p;
        }
#pragma unroll
      for (int itr = 0; itr < 8; itr++) {
        const int slot = itr * 64 + lane;
        const int d = slot >> 3, ch = slot & 7;
        bf16x8 v = *(const bf16x8*)&lEt[d * 72 + ch * 8];
        *(bf16x8*)(vT + dbase + (size_t)(half * 64 + d) * 1024 + ch * 8) = v;
      }
    }
  }
}

// ---------------- attention v8 (measured 124.02 config) ---------------------------
__global__ __launch_bounds__(256, 2) void attn_fwd(
    const short* __restrict__ qb, const short* __restrict__ kb,
    const short* __restrict__ vT, const float* __restrict__ temp,
    short* __restrict__ ob)
{
  __shared__ __align__(16) char lds[37888];
  const int t = threadIdx.x;
  const int wv = t >> 6, lane = t & 63;
  const int c = lane & 15, g = lane >> 4;
  const int bid = blockIdx.x;
  const int work = (bid & 7) * 96 + (bid >> 3);   // bijective: 768 = 8 XCD x 96
  const int bh = work >> 4, qt = work & 15;
  const int b = bh / 6, h = bh % 6;
  short* myP = (short*)(lds + 32768 + wv * 1280);  // [16 q][40 shorts]

  const short* qbase = qb + (size_t)bh * 131072;
  const char*  kgl   = (const char*)(kb + (size_t)bh * 131072);
  const char*  vgl   = (const char*)(vT + (size_t)bh * 131072);
  const int q0 = qt * 64 + wv * 16;

  bf16x8 qf[4];
#pragma unroll
  for (int dc = 0; dc < 4; dc++)
    qf[dc] = *(const bf16x8*)(qbase + (size_t)(q0 + c) * 128 + dc*32 + g*8);

  int koff[8], voff[8];
#pragma unroll
  for (int kf = 0; kf < 2; kf++)
#pragma unroll
    for (int kc = 0; kc < 4; kc++) {
      const int row = kf * 16 + c;
      koff[kf*4 + kc] = row * 256 + ((kc * 64 + g * 16) ^ ((row & 7) << 4));
    }
#pragma unroll
  for (int df = 0; df < 8; df++) {
    const int d = df * 16 + c;
    voff[df] = d * 64 + ((g * 16) ^ (((d >> 1) & 3) << 4));
  }
  const int paoff = c * 40 + g * 8;
  const int pwbase = 4 * g * 40 + c;

  const float t2 = temp[h] * 1.44269504088896341f;
  const f32x4 z4 = {0.f, 0.f, 0.f, 0.f};
  f32x4 oacc[8];
#pragma unroll
  for (int j = 0; j < 8; j++) oacc[j] = z4;
  float lsum[4] = {0.f, 0.f, 0.f, 0.f};

  auto STAGE = [&](int kt, int p) {
    char* kbuf = lds + p * 16384;
    char* vbuf = kbuf + 8192;
#pragma unroll
    for (int i = 0; i < 2; i++) {
      const int ob_ = (i * 4 + wv) * 1024;
      const int o = ob_ + lane * 16;
      {
        const int row = o >> 8;
        const int cb = (o & 255) ^ ((row & 7) << 4);
        gload16(kgl + (size_t)(kt + row) * 256 + cb, kbuf + ob_);
      }
      {
        const int d = o >> 6;
        const int cb = (o & 63) ^ (((d >> 1) & 3) << 4);
        gload16(vgl + (size_t)d * 2048 + (size_t)kt * 2 + cb, vbuf + ob_);
      }
    }
  };
  auto COMPUTE = [&](int p) {
    char* kbuf = lds + p * 16384;
    char* vbuf = kbuf + 8192;
    f32x4 s[2] = {z4, z4};
#pragma unroll
    for (int kf = 0; kf < 2; kf++) {
      bf16x8 kfr[4];
#pragma unroll
      for (int kc = 0; kc < 4; kc++)
        kfr[kc] = *(const bf16x8*)(kbuf + koff[kf*4 + kc]);
      __builtin_amdgcn_s_setprio(1);
#pragma unroll
      for (int kc = 0; kc < 4; kc++)
        s[kf] = MFMA16(qf[kc], kfr[kc], s[kf]);
      __builtin_amdgcn_s_setprio(0);
    }
    bf16x8 vf[8];
#pragma unroll
    for (int df = 0; df < 8; df++)
      vf[df] = *(const bf16x8*)(vbuf + voff[df]);
#pragma unroll
    for (int kf = 0; kf < 2; kf++)
#pragma unroll
      for (int r = 0; r < 4; r++) {
        float pv = __builtin_amdgcn_exp2f(s[kf][r] * t2);
        lsum[r] += pv;
        myP[pwbase + r * 40 + kf * 16] = f2bf(pv);
      }
    bf16x8 pa = *(const bf16x8*)&myP[paoff];
    __builtin_amdgcn_s_setprio(1);
#pragma unroll
    for (int df = 0; df < 8; df++)
      oacc[df] = MFMA16(pa, vf[df], oacc[df]);
    __builtin_amdgcn_s_setprio(0);
  };

  STAGE(0, 0);
  WAITV(0); BAR();
#pragma unroll 2
  for (int it = 0; it < 31; it++) {
    STAGE((it + 1) * 32, (it + 1) & 1);
    WAITV(4); BAR();
    COMPUTE(it & 1);
    BAR();
  }
  WAITV(0); BAR();
  COMPUTE(1);

  float rin[4];
#pragma unroll
  for (int r = 0; r < 4; r++) {
    float s = lsum[r];
    s += __shfl_xor(s, 1); s += __shfl_xor(s, 2);
    s += __shfl_xor(s, 4); s += __shfl_xor(s, 8);
    rin[r] = 1.0f / s;
  }
  __syncthreads();
  short* myO = (short*)(lds + wv * 4352);
#pragma unroll
  for (int df = 0; df < 8; df++)
#pragma unroll
    for (int r = 0; r < 4; r++)
      myO[(4*g + r) * 136 + df*16 + c] = f2bf(oacc[df][r] * rin[r]);
  const size_t obase_ = ((size_t)(b * 1024 + q0)) * 768 + h * 128;
#pragma unroll
  for (int it = 0; it < 4; it++) {
    const int slot = it * 64 + lane;
    const int row = slot >> 4, ch = slot & 15;
    bf16x8 v = *(const bf16x8*)&myO[row * 136 + ch * 8];
    *(bf16x8*)(ob + obase_ + (size_t)row * 768 + ch * 8) = v;
  }
}

// ---------------- proj GEMM v4 (measured 124.02 config): 128x256, BK=32, dbuf -----
__global__ __launch_bounds__(256, 2) void proj_gemm(
    const short* __restrict__ ob, const short* __restrict__ wpb,
    const float* __restrict__ bias, float* __restrict__ out)
{
  __shared__ __align__(16) char lds[49152];
  const int t = threadIdx.x;
  const int wv = t >> 6, lane = t & 63;
  const int c = lane & 15, g = lane >> 4;
  const int wm = wv >> 1, wn = wv & 1;
  const int bm = blockIdx.x, bj = blockIdx.y;
  const short* W = wpb + (size_t)bj * 196608;
  const int am0 = bm * 128;
  const f32x4 z4 = {0.f, 0.f, 0.f, 0.f};
  f32x4 acc[4][8];
#pragma unroll
  for (int i = 0; i < 4; i++)
#pragma unroll
    for (int j = 0; j < 8; j++) acc[i][j] = z4;

  int aoff[4], boff[8];
#pragma unroll
  for (int mf = 0; mf < 4; mf++) {
    const int row = wm * 64 + mf * 16 + c;
    aoff[mf] = row * 64 + ((g * 16) ^ ((row & 3) << 4));
  }
#pragma unroll
  for (int nf = 0; nf < 8; nf++) {
    const int row = wn * 128 + nf * 16 + c;
    boff[nf] = row * 64 + ((g * 16) ^ ((row & 3) << 4));
  }

  auto STAGE = [&](int kt, int p) {
    char* lA = lds + p * 24576;
    char* lB = lA + 8192;
#pragma unroll
    for (int i = 0; i < 2; i++) {
      const int cb0 = (i * 4 + wv) * 1024;
      const int o = cb0 + lane * 16;
      const int row = o >> 6;
      const int cbyte = (o & 63) ^ ((row & 3) << 4);
      gload16((const char*)ob + ((size_t)(am0 + row) * 768 + kt) * 2 + cbyte, lA + cb0);
    }
#pragma unroll
    for (int i = 0; i < 4; i++) {
      const int cb0 = (i * 4 + wv) * 1024;
      const int o = cb0 + lane * 16;
      const int row = o >> 6;
      const int cbyte = (o & 63) ^ ((row & 3) << 4);
      gload16((const char*)W + ((size_t)row * 768 + kt) * 2 + cbyte, lB + cb0);
    }
  };
  auto COMPUTE = [&](int p) {
    char* lA = lds + p * 24576;
    char* lB = lA + 8192;
    bf16x8 af[4], bfr[8];
#pragma unroll
    for (int mf = 0; mf < 4; mf++) af[mf] = *(const bf16x8*)(lA + aoff[mf]);
#pragma unroll
    for (int nf = 0; nf < 8; nf++) bfr[nf] = *(const bf16x8*)(lB + boff[nf]);
    __builtin_amdgcn_s_setprio(1);
#pragma unroll
    for (int mf = 0; mf < 4; mf++)
#pragma unroll
      for (int nf = 0; nf < 8; nf++)
        acc[mf][nf] = MFMA16(af[mf], bfr[nf], acc[mf][nf]);
    __builtin_amdgcn_s_setprio(0);
  };

  STAGE(0, 0);
  WAITV(0); BAR();
#pragma unroll 2
  for (int it = 0; it < 23; it++) {
    STAGE((it + 1) * 32, (it + 1) & 1);
    WAITV(6); BAR();
    COMPUTE(it & 1);
    BAR();
  }
  WAITV(0); BAR();
  COMPUTE(1);

  const int col0 = bj * 256 + wn * 128;
  float bb[8];
#pragma unroll
  for (int nf = 0; nf < 8; nf++) bb[nf] = bias[col0 + nf*16 + c];
#pragma unroll
  for (int mf = 0; mf < 4; mf++)
#pragma unroll
    for (int nf = 0; nf < 8; nf++)
#pragma unroll
      for (int r = 0; r < 4; r++)
        out[(size_t)(am0 + wm*64 + mf*16 + 4*g + r) * 768 + col0 + nf*16 + c]
            = acc[mf][nf][r] + bb[nf];
}

extern "C" void kernel_launch(void* const* d_in, const int* in_sizes, int n_in,
                              void* d_out, int out_size, void* d_ws, size_t ws_size,
                              hipStream_t stream) {
  const float* x    = (const float*)d_in[0];
  const float* y    = (const float*)d_in[1];
  const float* wq   = (const float*)d_in[2];
  const float* wkv  = (const float*)d_in[3];
  const float* wp   = (const float*)d_in[4];
  const float* bias = (const float*)d_in[5];
  const float* temp = (const float*)d_in[6];

  short* ws   = (short*)d_ws;
  short* xb   = ws;
  short* yb   = xb + 6291456;
  short* wqb  = yb + 6291456;
  short* wkvb = wqb + 589824;
  short* wpb  = wkvb + 1179648;
  short* qb   = wpb + 589824;
  short* kb   = qb + 6291456;
  short* vT   = kb + 6291456;
  short* ob   = vT + 6291456;

  convert_all<<<dim3(1024), dim3(256), 0, stream>>>(x, y, wq, wkv, wp, ws);
  qkv_gemm<<<dim3(64, 9), dim3(256), 0, stream>>>(xb, yb, wqb, wkvb, qb, kb, vT);
  attn_fwd<<<dim3(768), dim3(256), 0, stream>>>(qb, kb, vT, temp, ob);
  proj_gemm<<<dim3(64, 3), dim3(256), 0, stream>>>(ob, wpb, bias, (float*)d_out);
}